// Round 2
// baseline (256.146 us; speedup 1.0000x reference)
//
#include <hip/hip_runtime.h>
#include <hip/hip_bf16.h>

// (B,H,S,D) = (2,8,4096,64)
#define S_   4096
#define D_   64
#define BH_  16
#define QW   32      // q rows per wave
#define QBLK 128     // q rows per block (4 waves)
#define KVB  64

typedef __attribute__((ext_vector_type(8)))  short short8_t;   // 8 bf16 (MFMA A/B frag)
typedef __attribute__((ext_vector_type(16))) float f32x16;     // 32x32 MFMA C/D frag
#define QSCALE 0.18033688011112042f   /* (1/8) * log2(e): scores come out in log2 domain */

__device__ __forceinline__ unsigned short f2bf(float f) {
  unsigned u = __float_as_uint(f);
  u += 0x7fffu + ((u >> 16) & 1u);   // RTNE
  return (unsigned short)(u >> 16);
}

// o[i] = bf16((a[i]+b[i])*scale)
__global__ void addcvt2_kernel(const float* __restrict__ a, const float* __restrict__ b,
                               unsigned short* __restrict__ o, float scale, int n) {
  int i = (blockIdx.x * blockDim.x + threadIdx.x) * 4;
  if (i >= n) return;
  float4 x = *(const float4*)(a + i);
  float4 y = *(const float4*)(b + i);
  ushort4 r;
  r.x = f2bf((x.x + y.x) * scale); r.y = f2bf((x.y + y.y) * scale);
  r.z = f2bf((x.z + y.z) * scale); r.w = f2bf((x.w + y.w) * scale);
  *(ushort4*)(o + i) = r;
}

// Vt[bh][d][s] = bf16(v_a + v_s), transposed per head (LDS-tiled)
__global__ void vtrans_kernel(const float* __restrict__ va, const float* __restrict__ vs,
                              unsigned short* __restrict__ vt) {
  __shared__ __align__(16) unsigned short t[D_][72];
  int bh = blockIdx.y;
  int s0 = blockIdx.x * 64;
  int tid = threadIdx.x;
  int row16 = tid >> 4;
  int col4  = (tid & 15) * 4;
#pragma unroll
  for (int p = 0; p < 4; ++p) {
    int srow = p * 16 + row16;
    float4 x = *(const float4*)(va + ((size_t)bh * S_ + s0 + srow) * D_ + col4);
    float4 y = *(const float4*)(vs + ((size_t)bh * S_ + s0 + srow) * D_ + col4);
    t[col4 + 0][srow] = f2bf(x.x + y.x);
    t[col4 + 1][srow] = f2bf(x.y + y.y);
    t[col4 + 2][srow] = f2bf(x.z + y.z);
    t[col4 + 3][srow] = f2bf(x.w + y.w);
  }
  __syncthreads();
#pragma unroll
  for (int r = 0; r < 2; ++r) {
    int e = (r * 256 + tid) * 8;
    int d = e >> 6, sc = e & 63;
    short8_t v = *(const short8_t*)&t[d][sc];
    *(short8_t*)(vt + ((size_t)bh * D_ + d) * S_ + s0 + sc) = v;
  }
}

// mask -> additive bias in log2 domain (0 or -1e9)
__global__ void bias_kernel(const int* __restrict__ m, float* __restrict__ fb, int n) {
  int i = blockIdx.x * 256 + threadIdx.x;
  if (i < n) fb[i] = m[i] ? 0.0f : -1.0e9f;
}

// Flash attention, swapped-QK^T 32x32x16 structure.
// Wave w owns q rows bq + w*32 + (lane&31); scores/P are lane-local per q (col=lane&31).
__global__ __launch_bounds__(256, 2) void attn_kernel(
    const unsigned short* __restrict__ Qb, const unsigned short* __restrict__ Kb,
    const unsigned short* __restrict__ Vt, const float* __restrict__ fbias,
    float* __restrict__ out) {
  // unpadded 64x64 bf16 tiles; 16B-group XOR swizzle g^=(row&7) balances bank quads
  __shared__ __align__(16) unsigned short lK[64 * 64];
  __shared__ __align__(16) unsigned short lV[64 * 64];

  const int tid  = threadIdx.x;
  const int wave = tid >> 6;
  const int lane = tid & 63;
  const int l31  = lane & 31;
  const int h5   = lane >> 5;
  const int rsw  = l31 & 7;
  const int bh   = blockIdx.y;
  const int qrow = blockIdx.x * QBLK + wave * QW + l31;

  // Q fragments (B-operand): qf[t] = Q[qrow][t*16 + h5*8 .. +7]
  const unsigned short* qp = Qb + ((size_t)bh * S_ + qrow) * D_ + h5 * 8;
  short8_t qf[4];
#pragma unroll
  for (int t4 = 0; t4 < 4; ++t4) qf[t4] = *(const short8_t*)(qp + t4 * 16);

  const unsigned short* gk0 = Kb + (size_t)bh * S_ * D_;
  const unsigned short* gv0 = Vt + (size_t)bh * D_ * S_;
  const float* fb = fbias + (size_t)(bh >> 3) * S_;

  // staging: chunk c -> row=c>>3, group g=c&7; K src is contiguous (c*8 shorts)
  const int c0 = tid, c1 = 256 + tid;
  const int dst0 = (c0 >> 3) * 64 + (((c0 & 7) ^ ((c0 >> 3) & 7)) * 8);
  const int dst1 = (c1 >> 3) * 64 + (((c1 & 7) ^ ((c1 >> 3) & 7)) * 8);
  const int vs0 = (c0 >> 3) * S_ + (c0 & 7) * 8;
  const int vs1 = (c1 >> 3) * S_ + (c1 & 7) * 8;

  f32x16 acc0 = (f32x16)(0.0f), acc1 = (f32x16)(0.0f);
  float mrow = -1e30f, lrow = 0.0f;

  // prefetch tile 0 into registers
  short8_t pk0 = *(const short8_t*)(gk0 + c0 * 8);
  short8_t pk1 = *(const short8_t*)(gk0 + c1 * 8);
  short8_t pv0 = *(const short8_t*)(gv0 + vs0);
  short8_t pv1 = *(const short8_t*)(gv0 + vs1);

  for (int kv = 0; kv < S_; kv += KVB) {
    __syncthreads();                       // previous compute done reading LDS
    *(short8_t*)&lK[dst0] = pk0;
    *(short8_t*)&lK[dst1] = pk1;
    *(short8_t*)&lV[dst0] = pv0;
    *(short8_t*)&lV[dst1] = pv1;
    if (kv + KVB < S_) {                   // issue next-tile loads; land during compute
      const unsigned short* nk = gk0 + (size_t)(kv + KVB) * D_;
      pk0 = *(const short8_t*)(nk + c0 * 8);
      pk1 = *(const short8_t*)(nk + c1 * 8);
      pv0 = *(const short8_t*)(gv0 + (kv + KVB) + vs0);
      pv1 = *(const short8_t*)(gv0 + (kv + KVB) + vs1);
    }
    __syncthreads();                       // tiles visible

    // ---- S^T = K Q^T : D[key][q], col=lane&31=q, key = n*32 + (reg&3)+8*(reg>>2)+4*h5
    f32x16 s0v = (f32x16)(0.0f), s1v = (f32x16)(0.0f);
#pragma unroll
    for (int t4 = 0; t4 < 4; ++t4) {
      int g = ((2 * t4 + h5) ^ rsw) * 8;
      short8_t kf0 = *(const short8_t*)&lK[l31 * 64 + g];
      short8_t kf1 = *(const short8_t*)&lK[(32 + l31) * 64 + g];
      s0v = __builtin_amdgcn_mfma_f32_32x32x16_bf16(kf0, qf[t4], s0v, 0, 0, 0);
      s1v = __builtin_amdgcn_mfma_f32_32x32x16_bf16(kf1, qf[t4], s1v, 0, 0, 0);
    }

    // ---- bias (masked -> -1e9) ; scores already in log2 domain
    float p[32];
#pragma unroll
    for (int rg = 0; rg < 4; ++rg) {
      float4 b0 = *(const float4*)(fb + kv + rg * 8 + h5 * 4);
      float4 b1 = *(const float4*)(fb + kv + 32 + rg * 8 + h5 * 4);
      p[rg * 4 + 0] = s0v[rg * 4 + 0] + b0.x;  p[rg * 4 + 1] = s0v[rg * 4 + 1] + b0.y;
      p[rg * 4 + 2] = s0v[rg * 4 + 2] + b0.z;  p[rg * 4 + 3] = s0v[rg * 4 + 3] + b0.w;
      p[16 + rg * 4 + 0] = s1v[rg * 4 + 0] + b1.x;  p[16 + rg * 4 + 1] = s1v[rg * 4 + 1] + b1.y;
      p[16 + rg * 4 + 2] = s1v[rg * 4 + 2] + b1.z;  p[16 + rg * 4 + 3] = s1v[rg * 4 + 3] + b1.w;
    }

    // ---- row max: in-lane tree + one cross-half exchange
    float tmx[16];
#pragma unroll
    for (int i = 0; i < 16; ++i) tmx[i] = fmaxf(p[i], p[i + 16]);
#pragma unroll
    for (int i = 0; i < 8; ++i) tmx[i] = fmaxf(tmx[i], tmx[i + 8]);
#pragma unroll
    for (int i = 0; i < 4; ++i) tmx[i] = fmaxf(tmx[i], tmx[i + 4]);
    float tm = fmaxf(fmaxf(tmx[0], tmx[1]), fmaxf(tmx[2], tmx[3]));
    tm = fmaxf(tm, __shfl_xor(tm, 32));

    // ---- defer-max (T13): only rescale when max grew past threshold
    if (__any(tm > mrow + 8.0f)) {
      float mnew = fmaxf(mrow, tm);
      float sc = __builtin_amdgcn_exp2f(mrow - mnew);
      mrow = mnew;
      lrow *= sc;
#pragma unroll
      for (int i = 0; i < 16; ++i) { acc0[i] *= sc; acc1[i] *= sc; }
    }

    // ---- p = 2^(s-m), partial sums (4-way tree to cut dep chain)
    float t0 = 0.f, t1 = 0.f, t2 = 0.f, t3 = 0.f;
#pragma unroll
    for (int i = 0; i < 32; i += 4) {
      p[i + 0] = __builtin_amdgcn_exp2f(p[i + 0] - mrow); t0 += p[i + 0];
      p[i + 1] = __builtin_amdgcn_exp2f(p[i + 1] - mrow); t1 += p[i + 1];
      p[i + 2] = __builtin_amdgcn_exp2f(p[i + 2] - mrow); t2 += p[i + 2];
      p[i + 3] = __builtin_amdgcn_exp2f(p[i + 3] - mrow); t3 += p[i + 3];
    }
    float ts = (t0 + t1) + (t2 + t3);
    ts += __shfl_xor(ts, 32);
    lrow += ts;

    // ---- pack P to bf16 pairs: pkw[n*8+rg*2+c] = keys n*32+rg*8+4*h5+2c (lo), +1 (hi)
    unsigned int pkw[16];
#pragma unroll
    for (int n = 0; n < 2; ++n)
#pragma unroll
      for (int rg = 0; rg < 4; ++rg) {
        __hip_bfloat162 a = __float22bfloat162_rn({p[n * 16 + rg * 4 + 0], p[n * 16 + rg * 4 + 1]});
        __hip_bfloat162 b = __float22bfloat162_rn({p[n * 16 + rg * 4 + 2], p[n * 16 + rg * 4 + 3]});
        pkw[n * 8 + rg * 2 + 0] = *(unsigned int*)&a;
        pkw[n * 8 + rg * 2 + 1] = *(unsigned int*)&b;
      }

    // ---- O^T += V^T P : per key-step kt, B-frag needs keys kt*16+h5*8..+7 for own q.
    // Half-swap redistribution: one shfl_xor(32) pair per kt (supply what the partner needs).
#pragma unroll
    for (int kt = 0; kt < 4; ++kt) {
      int n = kt >> 1, k1 = kt & 1;
      unsigned int sA = pkw[n * 8 + (2 * k1 + h5) * 2 + 0];
      unsigned int sB = pkw[n * 8 + (2 * k1 + h5) * 2 + 1];
      unsigned int xA = pkw[n * 8 + (2 * k1 + (h5 ^ 1)) * 2 + 0];
      unsigned int xB = pkw[n * 8 + (2 * k1 + (h5 ^ 1)) * 2 + 1];
      unsigned int pA = (unsigned int)__shfl_xor((int)xA, 32);
      unsigned int pB = (unsigned int)__shfl_xor((int)xB, 32);
      union { unsigned int u[4]; short8_t v; } bb;
      bb.u[0] = h5 ? pA : sA;   // keys from lower-half holders
      bb.u[1] = h5 ? pB : sB;
      bb.u[2] = h5 ? sA : pA;   // keys from upper-half holders
      bb.u[3] = h5 ? sB : pB;
      int gv = ((2 * kt + h5) ^ rsw) * 8;
      short8_t vf0 = *(const short8_t*)&lV[l31 * 64 + gv];
      short8_t vf1 = *(const short8_t*)&lV[(32 + l31) * 64 + gv];
      acc0 = __builtin_amdgcn_mfma_f32_32x32x16_bf16(vf0, bb.v, acc0, 0, 0, 0);
      acc1 = __builtin_amdgcn_mfma_f32_32x32x16_bf16(vf1, bb.v, acc1, 0, 0, 0);
    }
  }

  // ---- epilogue: O[q][d] = accO^T * (1/l);  d = n2*32 + rg*8 + h5*4 + i
  float inv = __builtin_amdgcn_rcpf(lrow);
  float* op = out + ((size_t)bh * S_ + qrow) * D_;
#pragma unroll
  for (int rg = 0; rg < 4; ++rg) {
    float4 o0, o1;
    o0.x = acc0[rg * 4 + 0] * inv; o0.y = acc0[rg * 4 + 1] * inv;
    o0.z = acc0[rg * 4 + 2] * inv; o0.w = acc0[rg * 4 + 3] * inv;
    o1.x = acc1[rg * 4 + 0] * inv; o1.y = acc1[rg * 4 + 1] * inv;
    o1.z = acc1[rg * 4 + 2] * inv; o1.w = acc1[rg * 4 + 3] * inv;
    *(float4*)(op + rg * 8 + h5 * 4) = o0;
    *(float4*)(op + 32 + rg * 8 + h5 * 4) = o1;
  }
}

extern "C" void kernel_launch(void* const* d_in, const int* in_sizes, int n_in,
                              void* d_out, int out_size, void* d_ws, size_t ws_size,
                              hipStream_t stream) {
  const float* q_a = (const float*)d_in[0];
  const float* k_a = (const float*)d_in[1];
  const float* v_a = (const float*)d_in[2];
  const float* q_s = (const float*)d_in[3];
  const float* k_s = (const float*)d_in[4];
  const float* v_s = (const float*)d_in[5];
  const int*   mask = (const int*)d_in[6];
  float* out = (float*)d_out;
  (void)in_sizes; (void)n_in; (void)out_size; (void)ws_size;

  const int N = BH_ * S_ * D_;
  unsigned short* qb = (unsigned short*)d_ws;
  unsigned short* kb = qb + N;
  unsigned short* vt = kb + N;
  float* fb = (float*)(vt + N);

  addcvt2_kernel<<<N / 1024, 256, 0, stream>>>(q_a, q_s, qb, QSCALE, N);
  addcvt2_kernel<<<N / 1024, 256, 0, stream>>>(k_a, k_s, kb, 1.0f, N);
  {
    dim3 g(S_ / 64, BH_);
    vtrans_kernel<<<g, 256, 0, stream>>>(v_a, v_s, vt);
  }
  bias_kernel<<<(2 * S_) / 256, 256, 0, stream>>>(mask, fb, 2 * S_);
  {
    dim3 g(S_ / QBLK, BH_);
    attn_kernel<<<g, 256, 0, stream>>>(qb, kb, vt, fb, out);
  }
}

// Round 4
// 227.018 us; speedup vs baseline: 1.1283x; 1.1283x over previous
//
#include <hip/hip_runtime.h>
#include <hip/hip_bf16.h>

// (B,H,S,D) = (2,8,4096,64)
#define S_   4096
#define D_   64
#define BH_  16
#define QW   32        // q rows per wave
#define QBLK 128       // q rows per block (4 waves)
#define KVB  64        // keys per tile
#define NCH  2         // kv chunks (grid z)
#define SCH  (S_ / NCH)   // 2048 keys per chunk
#define NT   (SCH / KVB)  // 32 tiles per chunk

typedef __attribute__((ext_vector_type(8)))  short short8_t;   // 8 bf16 (MFMA A/B frag)
typedef __attribute__((ext_vector_type(16))) float f32x16;     // 32x32 MFMA C/D frag
#define QSCALE 0.18033688011112042f   /* (1/8)*log2(e): scores in log2 domain */

__device__ __forceinline__ unsigned short f2bf(float f) {
  unsigned u = __float_as_uint(f);
  u += 0x7fffu + ((u >> 16) & 1u);   // RTNE
  return (unsigned short)(u >> 16);
}

__device__ __forceinline__ void glds16(const unsigned short* g, unsigned short* l) {
  __builtin_amdgcn_global_load_lds(
      (const __attribute__((address_space(1))) unsigned int*)g,
      (__attribute__((address_space(3))) unsigned int*)l, 16, 0, 0);
}

// o[i] = bf16((a[i]+b[i])*scale)
__global__ void addcvt2_kernel(const float* __restrict__ a, const float* __restrict__ b,
                               unsigned short* __restrict__ o, float scale, int n) {
  int i = (blockIdx.x * blockDim.x + threadIdx.x) * 4;
  if (i >= n) return;
  float4 x = *(const float4*)(a + i);
  float4 y = *(const float4*)(b + i);
  ushort4 r;
  r.x = f2bf((x.x + y.x) * scale); r.y = f2bf((x.y + y.y) * scale);
  r.z = f2bf((x.z + y.z) * scale); r.w = f2bf((x.w + y.w) * scale);
  *(ushort4*)(o + i) = r;
}

// Vt[bh][d][s] = bf16(v_a + v_s), transposed per head
__global__ void vtrans_kernel(const float* __restrict__ va, const float* __restrict__ vs,
                              unsigned short* __restrict__ vt) {
  __shared__ __align__(16) unsigned short t[D_][72];
  int bh = blockIdx.y;
  int s0 = blockIdx.x * 64;
  int tid = threadIdx.x;
  int row16 = tid >> 4;
  int col4  = (tid & 15) * 4;
#pragma unroll
  for (int p = 0; p < 4; ++p) {
    int srow = p * 16 + row16;
    float4 x = *(const float4*)(va + ((size_t)bh * S_ + s0 + srow) * D_ + col4);
    float4 y = *(const float4*)(vs + ((size_t)bh * S_ + s0 + srow) * D_ + col4);
    t[col4 + 0][srow] = f2bf(x.x + y.x);
    t[col4 + 1][srow] = f2bf(x.y + y.y);
    t[col4 + 2][srow] = f2bf(x.z + y.z);
    t[col4 + 3][srow] = f2bf(x.w + y.w);
  }
  __syncthreads();
#pragma unroll
  for (int r = 0; r < 2; ++r) {
    int e = (r * 256 + tid) * 8;
    int d = e >> 6, sc = e & 63;
    short8_t v = *(const short8_t*)&t[d][sc];
    *(short8_t*)(vt + ((size_t)bh * D_ + d) * S_ + s0 + sc) = v;
  }
}

// mask -> additive bias (0 or -1e9) applied in log2 domain
__global__ void bias_kernel(const int* __restrict__ m, float* __restrict__ fb, int n) {
  int i = blockIdx.x * 256 + threadIdx.x;
  if (i < n) fb[i] = m[i] ? 0.0f : -1.0e9f;
}

// Flash attention partial over one KV chunk. Swapped-QK^T 32x32x16, in-register softmax.
__global__ __launch_bounds__(256, 4) void attn_kernel(
    const unsigned short* __restrict__ Qb, const unsigned short* __restrict__ Kb,
    const unsigned short* __restrict__ Vt, const float* __restrict__ fbias,
    float* __restrict__ Oa, float* __restrict__ Ob, float2* __restrict__ Ml) {
  __shared__ __align__(16) unsigned short lK[2][64 * 64];
  __shared__ __align__(16) unsigned short lV[2][64 * 64];

  const int tid  = threadIdx.x;
  const int wave = tid >> 6;
  const int lane = tid & 63;
  const int l31  = lane & 31;
  const int h5   = lane >> 5;
  const int rsw  = l31 & 7;
  const int bh   = blockIdx.y;
  const int ch   = blockIdx.z;
  const int qrow = blockIdx.x * QBLK + wave * QW + l31;
  const int kv0  = ch * SCH;

  // Q fragments (B-operand): qf[t] = Q[qrow][t*16 + h5*8 .. +7]
  const unsigned short* qp = Qb + ((size_t)bh * S_ + qrow) * D_ + h5 * 8;
  short8_t qf[4];
#pragma unroll
  for (int t4 = 0; t4 < 4; ++t4) qf[t4] = *(const short8_t*)(qp + t4 * 16);

  const unsigned short* gk0 = Kb + ((size_t)bh * S_ + kv0) * D_;
  const unsigned short* gv0 = Vt + (size_t)bh * D_ * S_ + kv0;
  const float* fb = fbias + (size_t)(bh >> 3) * S_ + kv0;

  // staging geometry: 16B chunk c = r2*256+tid -> LDS row=c>>3, group g'=c&7 (linear dest);
  // global source pre-swizzled: group g = g' ^ (row&7)  [m173 pattern]
  int srcK[2], srcV[2], ldsB[2];
#pragma unroll
  for (int r2 = 0; r2 < 2; ++r2) {
    int c = r2 * 256 + tid;
    int row = c >> 3, g = (c & 7) ^ (row & 7);
    srcK[r2] = row * 64 + g * 8;
    srcV[r2] = row * S_ + g * 8;
    ldsB[r2] = r2 * 2048 + wave * 512;   // wave-uniform base (elems); HW adds lane*16B
  }

  f32x16 acc0 = (f32x16)(0.0f), acc1 = (f32x16)(0.0f);
  float mrow = -1e30f, lrow = 0.0f;

  // stage tile 0 into buf0
#pragma unroll
  for (int r2 = 0; r2 < 2; ++r2) {
    glds16(gk0 + srcK[r2], &lK[0][ldsB[r2]]);
    glds16(gv0 + srcV[r2], &lV[0][ldsB[r2]]);
  }
  __syncthreads();

  for (int t = 0; t < NT; ++t) {
    const int cur = t & 1;
    // issue prefetch of tile t+1 into the other buffer (lands during compute)
    if (t + 1 < NT) {
      const unsigned short* nk = gk0 + (size_t)(t + 1) * KVB * D_;
      const unsigned short* nv = gv0 + (t + 1) * KVB;
#pragma unroll
      for (int r2 = 0; r2 < 2; ++r2) {
        glds16(nk + srcK[r2], &lK[cur ^ 1][ldsB[r2]]);
        glds16(nv + srcV[r2], &lV[cur ^ 1][ldsB[r2]]);
      }
    }

    // ---- S^T = K Q^T : col=lane&31=q, key row = (rg&3)+8*(rg>>2)+4*h5
    f32x16 s0v = (f32x16)(0.0f), s1v = (f32x16)(0.0f);
#pragma unroll
    for (int t4 = 0; t4 < 4; ++t4) {
      int g = ((2 * t4 + h5) ^ rsw) * 8;
      short8_t kf0 = *(const short8_t*)&lK[cur][l31 * 64 + g];
      short8_t kf1 = *(const short8_t*)&lK[cur][(32 + l31) * 64 + g];
      s0v = __builtin_amdgcn_mfma_f32_32x32x16_bf16(kf0, qf[t4], s0v, 0, 0, 0);
      s1v = __builtin_amdgcn_mfma_f32_32x32x16_bf16(kf1, qf[t4], s1v, 0, 0, 0);
    }

    // ---- mask bias (log2 domain)
    float p[32];
#pragma unroll
    for (int rg = 0; rg < 4; ++rg) {
      float4 b0 = *(const float4*)(fb + t * KVB + rg * 8 + h5 * 4);
      float4 b1 = *(const float4*)(fb + t * KVB + 32 + rg * 8 + h5 * 4);
      p[rg * 4 + 0] = s0v[rg * 4 + 0] + b0.x;  p[rg * 4 + 1] = s0v[rg * 4 + 1] + b0.y;
      p[rg * 4 + 2] = s0v[rg * 4 + 2] + b0.z;  p[rg * 4 + 3] = s0v[rg * 4 + 3] + b0.w;
      p[16 + rg * 4 + 0] = s1v[rg * 4 + 0] + b1.x;  p[16 + rg * 4 + 1] = s1v[rg * 4 + 1] + b1.y;
      p[16 + rg * 4 + 2] = s1v[rg * 4 + 2] + b1.z;  p[16 + rg * 4 + 3] = s1v[rg * 4 + 3] + b1.w;
    }

    // ---- row max: in-lane tree + one cross-half exchange (shfl, verified R2)
    float tmx[16];
#pragma unroll
    for (int i = 0; i < 16; ++i) tmx[i] = fmaxf(p[i], p[i + 16]);
#pragma unroll
    for (int i = 0; i < 8; ++i) tmx[i] = fmaxf(tmx[i], tmx[i + 8]);
#pragma unroll
    for (int i = 0; i < 4; ++i) tmx[i] = fmaxf(tmx[i], tmx[i + 4]);
    float tm = fmaxf(fmaxf(tmx[0], tmx[1]), fmaxf(tmx[2], tmx[3]));
    tm = fmaxf(tm, __shfl_xor(tm, 32));

    // ---- defer-max (T13)
    if (__any(tm > mrow + 8.0f)) {
      float mnew = fmaxf(mrow, tm);
      float sc = __builtin_amdgcn_exp2f(mrow - mnew);
      mrow = mnew;
      lrow *= sc;
#pragma unroll
      for (int i = 0; i < 16; ++i) { acc0[i] *= sc; acc1[i] *= sc; }
    }

    // ---- p = 2^(s-m), partial sums
    float t0 = 0.f, t1 = 0.f, t2 = 0.f, t3 = 0.f;
#pragma unroll
    for (int i = 0; i < 32; i += 4) {
      p[i + 0] = __builtin_amdgcn_exp2f(p[i + 0] - mrow); t0 += p[i + 0];
      p[i + 1] = __builtin_amdgcn_exp2f(p[i + 1] - mrow); t1 += p[i + 1];
      p[i + 2] = __builtin_amdgcn_exp2f(p[i + 2] - mrow); t2 += p[i + 2];
      p[i + 3] = __builtin_amdgcn_exp2f(p[i + 3] - mrow); t3 += p[i + 3];
    }
    float ts = (t0 + t1) + (t2 + t3);
    ts += __shfl_xor(ts, 32);
    lrow += ts;

    // ---- pack P to bf16 pairs: pkw[n*8+rg*2+c] = keys n*32+rg*8+4*h5+2c, +1
    unsigned int pkw[16];
#pragma unroll
    for (int n = 0; n < 2; ++n)
#pragma unroll
      for (int rg = 0; rg < 4; ++rg) {
        __hip_bfloat162 a = __float22bfloat162_rn({p[n * 16 + rg * 4 + 0], p[n * 16 + rg * 4 + 1]});
        __hip_bfloat162 b = __float22bfloat162_rn({p[n * 16 + rg * 4 + 2], p[n * 16 + rg * 4 + 3]});
        pkw[n * 8 + rg * 2 + 0] = *(unsigned int*)&a;
        pkw[n * 8 + rg * 2 + 1] = *(unsigned int*)&b;
      }

    // ---- O^T += V^T P : half-swap redistribution via shfl (verified R2 mapping)
#pragma unroll
    for (int kt = 0; kt < 4; ++kt) {
      int n = kt >> 1, k1 = kt & 1;
      unsigned int sA = pkw[n * 8 + (2 * k1 + h5) * 2 + 0];
      unsigned int sB = pkw[n * 8 + (2 * k1 + h5) * 2 + 1];
      unsigned int xA = pkw[n * 8 + (2 * k1 + (h5 ^ 1)) * 2 + 0];
      unsigned int xB = pkw[n * 8 + (2 * k1 + (h5 ^ 1)) * 2 + 1];
      unsigned int pA = (unsigned int)__shfl_xor((int)xA, 32);
      unsigned int pB = (unsigned int)__shfl_xor((int)xB, 32);
      union { unsigned int u[4]; short8_t v; } bb;
      bb.u[0] = h5 ? pA : sA;   // keys from lower-half holders
      bb.u[1] = h5 ? pB : sB;
      bb.u[2] = h5 ? sA : pA;   // keys from upper-half holders
      bb.u[3] = h5 ? sB : pB;
      int gv = ((2 * kt + h5) ^ rsw) * 8;
      short8_t vf0 = *(const short8_t*)&lV[cur][l31 * 64 + gv];
      short8_t vf1 = *(const short8_t*)&lV[cur][(32 + l31) * 64 + gv];
      acc0 = __builtin_amdgcn_mfma_f32_32x32x16_bf16(vf0, bb.v, acc0, 0, 0, 0);
      acc1 = __builtin_amdgcn_mfma_f32_32x32x16_bf16(vf1, bb.v, acc1, 0, 0, 0);
    }

    __syncthreads();   // drains prefetch (vmcnt) + separates buffers
  }

  // ---- epilogue: unnormalized partial O + (m,l) stats
  float* Op = (ch == 0 ? Oa : Ob);
  float* op = Op + ((size_t)bh * S_ + qrow) * D_;
#pragma unroll
  for (int rg = 0; rg < 4; ++rg) {
    float4 o0, o1;
    o0.x = acc0[rg * 4 + 0]; o0.y = acc0[rg * 4 + 1];
    o0.z = acc0[rg * 4 + 2]; o0.w = acc0[rg * 4 + 3];
    o1.x = acc1[rg * 4 + 0]; o1.y = acc1[rg * 4 + 1];
    o1.z = acc1[rg * 4 + 2]; o1.w = acc1[rg * 4 + 3];
    *(float4*)(op + rg * 8 + h5 * 4) = o0;
    *(float4*)(op + 32 + rg * 8 + h5 * 4) = o1;
  }
  if (h5 == 0) {
    float2 st; st.x = mrow; st.y = lrow;
    Ml[(size_t)ch * (BH_ * S_) + (size_t)bh * S_ + qrow] = st;
  }
}

// merge two KV-chunk partials: out = (O0*w0 + O1*w1) / (l0*w0 + l1*w1), wi = 2^(mi - M)
__global__ void combine_kernel(const float* __restrict__ O1, const float2* __restrict__ Ml,
                               float* __restrict__ out) {
  int gid = blockIdx.x * 256 + threadIdx.x;   // (row, 16-d quarter)
  int row = gid >> 2, qd = (gid & 3) * 16;
  float2 a = Ml[row];                    // chunk 0
  float2 b = Ml[BH_ * S_ + row];         // chunk 1
  float M = fmaxf(a.x, b.x);
  float w0 = exp2f(a.x - M), w1 = exp2f(b.x - M);
  float inv = 1.0f / (a.y * w0 + b.y * w1);
  w0 *= inv; w1 *= inv;
  const float4* p0 = (const float4*)(out + (size_t)row * D_ + qd);  // chunk0 partial in out
  const float4* p1 = (const float4*)(O1 + (size_t)row * D_ + qd);
  float4* po = (float4*)(out + (size_t)row * D_ + qd);
#pragma unroll
  for (int i = 0; i < 4; ++i) {
    float4 x = p0[i], y = p1[i];
    float4 r;
    r.x = x.x * w0 + y.x * w1; r.y = x.y * w0 + y.y * w1;
    r.z = x.z * w0 + y.z * w1; r.w = x.w * w0 + y.w * w1;
    po[i] = r;
  }
}

extern "C" void kernel_launch(void* const* d_in, const int* in_sizes, int n_in,
                              void* d_out, int out_size, void* d_ws, size_t ws_size,
                              hipStream_t stream) {
  const float* q_a = (const float*)d_in[0];
  const float* k_a = (const float*)d_in[1];
  const float* v_a = (const float*)d_in[2];
  const float* q_s = (const float*)d_in[3];
  const float* k_s = (const float*)d_in[4];
  const float* v_s = (const float*)d_in[5];
  const int*   mask = (const int*)d_in[6];
  float* out = (float*)d_out;
  (void)in_sizes; (void)n_in; (void)out_size; (void)ws_size;

  const int N = BH_ * S_ * D_;   // 4,194,304
  unsigned short* qb = (unsigned short*)d_ws;
  unsigned short* kb = qb + N;
  unsigned short* vt = kb + N;
  float* fb = (float*)(vt + N);          // 2*S_ floats
  float* O1 = fb + 2 * S_;               // N floats (chunk-1 partial; chunk-0 -> out)
  float2* ml = (float2*)(O1 + N);        // NCH * BH_*S_ float2

  addcvt2_kernel<<<N / 1024, 256, 0, stream>>>(q_a, q_s, qb, QSCALE, N);
  addcvt2_kernel<<<N / 1024, 256, 0, stream>>>(k_a, k_s, kb, 1.0f, N);
  {
    dim3 g(S_ / 64, BH_);
    vtrans_kernel<<<g, 256, 0, stream>>>(v_a, v_s, vt);
  }
  bias_kernel<<<(2 * S_) / 256, 256, 0, stream>>>(mask, fb, 2 * S_);
  {
    dim3 g(S_ / QBLK, BH_, NCH);
    attn_kernel<<<g, 256, 0, stream>>>(qb, kb, vt, fb, out, O1, ml);
  }
  combine_kernel<<<(BH_ * S_ * 4) / 256, 256, 0, stream>>>(O1, ml, out);
}

// Round 6
// 215.406 us; speedup vs baseline: 1.1891x; 1.0539x over previous
//
#include <hip/hip_runtime.h>
#include <hip/hip_bf16.h>

// (B,H,S,D) = (2,8,4096,64)
#define S_   4096
#define D_   64
#define BH_  16
#define QW   64        // q rows per wave (two 32-col MFMA blocks)
#define QBLK 256       // q rows per block (4 waves)
#define KVB  64        // keys per tile
#define NCH  2         // kv chunks (grid z)
#define SCH  (S_ / NCH)   // 2048 keys per chunk
#define NT   (SCH / KVB)  // 32 tiles per chunk

typedef __attribute__((ext_vector_type(8)))  short short8_t;   // 8 bf16 (MFMA A/B frag)
typedef __attribute__((ext_vector_type(16))) float f32x16;     // 32x32 MFMA C/D frag
#define QSCALE 0.18033688011112042f   /* (1/8)*log2(e): scores in log2 domain */

__device__ __forceinline__ unsigned short f2bf(float f) {
  unsigned u = __float_as_uint(f);
  u += 0x7fffu + ((u >> 16) & 1u);   // RTNE
  return (unsigned short)(u >> 16);
}

__device__ __forceinline__ void glds16(const unsigned short* g, unsigned short* l) {
  __builtin_amdgcn_global_load_lds(
      (const __attribute__((address_space(1))) unsigned int*)g,
      (__attribute__((address_space(3))) unsigned int*)l, 16, 0, 0);
}

// o[i] = bf16((a[i]+b[i])*scale)
__global__ void addcvt2_kernel(const float* __restrict__ a, const float* __restrict__ b,
                               unsigned short* __restrict__ o, float scale, int n) {
  int i = (blockIdx.x * blockDim.x + threadIdx.x) * 4;
  if (i >= n) return;
  float4 x = *(const float4*)(a + i);
  float4 y = *(const float4*)(b + i);
  ushort4 r;
  r.x = f2bf((x.x + y.x) * scale); r.y = f2bf((x.y + y.y) * scale);
  r.z = f2bf((x.z + y.z) * scale); r.w = f2bf((x.w + y.w) * scale);
  *(ushort4*)(o + i) = r;
}

// Vt[bh][d][s] = bf16(v_a + v_s), transposed per head
__global__ void vtrans_kernel(const float* __restrict__ va, const float* __restrict__ vs,
                              unsigned short* __restrict__ vt) {
  __shared__ __align__(16) unsigned short t[D_][72];
  int bh = blockIdx.y;
  int s0 = blockIdx.x * 64;
  int tid = threadIdx.x;
  int row16 = tid >> 4;
  int col4  = (tid & 15) * 4;
#pragma unroll
  for (int p = 0; p < 4; ++p) {
    int srow = p * 16 + row16;
    float4 x = *(const float4*)(va + ((size_t)bh * S_ + s0 + srow) * D_ + col4);
    float4 y = *(const float4*)(vs + ((size_t)bh * S_ + s0 + srow) * D_ + col4);
    t[col4 + 0][srow] = f2bf(x.x + y.x);
    t[col4 + 1][srow] = f2bf(x.y + y.y);
    t[col4 + 2][srow] = f2bf(x.z + y.z);
    t[col4 + 3][srow] = f2bf(x.w + y.w);
  }
  __syncthreads();
#pragma unroll
  for (int r = 0; r < 2; ++r) {
    int e = (r * 256 + tid) * 8;
    int d = e >> 6, sc = e & 63;
    short8_t v = *(const short8_t*)&t[d][sc];
    *(short8_t*)(vt + ((size_t)bh * D_ + d) * S_ + s0 + sc) = v;
  }
}

// mask -> additive bias (0 or -1e9) applied in log2 domain
__global__ void bias_kernel(const int* __restrict__ m, float* __restrict__ fb, int n) {
  int i = blockIdx.x * 256 + threadIdx.x;
  if (i < n) fb[i] = m[i] ? 0.0f : -1.0e9f;
}

// Flash attention partial over one KV chunk. Swapped-QK^T 32x32x16, two q-blocks/wave.
__global__ __launch_bounds__(256, 2) void attn_kernel(
    const unsigned short* __restrict__ Qb, const unsigned short* __restrict__ Kb,
    const unsigned short* __restrict__ Vt, const float* __restrict__ fbias,
    float* __restrict__ Oa, float* __restrict__ Ob, float2* __restrict__ Ml) {
  __shared__ __align__(16) unsigned short lK[2][64 * 64];
  __shared__ __align__(16) unsigned short lV[2][64 * 64];

  const int tid  = threadIdx.x;
  const int wave = tid >> 6;
  const int lane = tid & 63;
  const int l31  = lane & 31;
  const int h5   = lane >> 5;
  const int rsw  = l31 & 7;
  const int bh   = blockIdx.y;
  const int ch   = blockIdx.z;
  const int qrow0 = blockIdx.x * QBLK + wave * QW + l31;   // q-block 0; +32 for q-block 1
  const int kv0  = ch * SCH;

  // Q fragments (B-operand): qf[qb][t4] = Q[qrow0 + 32*qb][t4*16 + h5*8 .. +7]
  short8_t qf[2][4];
#pragma unroll
  for (int qb = 0; qb < 2; ++qb) {
    const unsigned short* qp = Qb + ((size_t)bh * S_ + qrow0 + 32 * qb) * D_ + h5 * 8;
#pragma unroll
    for (int t4 = 0; t4 < 4; ++t4) qf[qb][t4] = *(const short8_t*)(qp + t4 * 16);
  }

  const unsigned short* gk0 = Kb + ((size_t)bh * S_ + kv0) * D_;
  const unsigned short* gv0 = Vt + (size_t)bh * D_ * S_ + kv0;
  const float* fb = fbias + (size_t)(bh >> 3) * S_ + kv0;

  // staging: 16B chunk c = r2*256+tid -> LDS row=c>>3, group g'=c&7 (linear dest);
  // global source pre-swizzled g = g' ^ (row&7)  [m173 pattern]
  int srcK[2], srcV[2], ldsB[2];
#pragma unroll
  for (int r2 = 0; r2 < 2; ++r2) {
    int c = r2 * 256 + tid;
    int row = c >> 3, g = (c & 7) ^ (row & 7);
    srcK[r2] = row * 64 + g * 8;
    srcV[r2] = row * S_ + g * 8;
    ldsB[r2] = r2 * 2048 + wave * 512;   // wave-uniform base; HW adds lane*16B
  }

  f32x16 acc0[2], acc1[2];
  float mrow[2], lrow[2];
#pragma unroll
  for (int qb = 0; qb < 2; ++qb) {
    acc0[qb] = (f32x16)(0.0f); acc1[qb] = (f32x16)(0.0f);
    mrow[qb] = -1e30f; lrow[qb] = 0.0f;
  }

  // stage tile 0 into buf0
#pragma unroll
  for (int r2 = 0; r2 < 2; ++r2) {
    glds16(gk0 + srcK[r2], &lK[0][ldsB[r2]]);
    glds16(gv0 + srcV[r2], &lV[0][ldsB[r2]]);
  }
  __syncthreads();

  for (int t = 0; t < NT; ++t) {
    const int cur = t & 1;
    if (t + 1 < NT) {   // prefetch next tile into other buffer (lands during compute)
      const unsigned short* nk = gk0 + (size_t)(t + 1) * KVB * D_;
      const unsigned short* nv = gv0 + (t + 1) * KVB;
#pragma unroll
      for (int r2 = 0; r2 < 2; ++r2) {
        glds16(nk + srcK[r2], &lK[cur ^ 1][ldsB[r2]]);
        glds16(nv + srcV[r2], &lV[cur ^ 1][ldsB[r2]]);
      }
    }

    // ---- mask bias -> MFMA C-init (score = qk + bias accumulates in-place)
    const float* fbt = fb + t * KVB;
    f32x16 sv0[2], sv1[2];   // [qb]: keys 0-31 / 32-63 of the tile
#pragma unroll
    for (int rg = 0; rg < 4; ++rg) {
      float4 b0 = *(const float4*)(fbt + rg * 8 + h5 * 4);
      float4 b1 = *(const float4*)(fbt + 32 + rg * 8 + h5 * 4);
#pragma unroll
      for (int qb = 0; qb < 2; ++qb) {
        sv0[qb][rg * 4 + 0] = b0.x; sv0[qb][rg * 4 + 1] = b0.y;
        sv0[qb][rg * 4 + 2] = b0.z; sv0[qb][rg * 4 + 3] = b0.w;
        sv1[qb][rg * 4 + 0] = b1.x; sv1[qb][rg * 4 + 1] = b1.y;
        sv1[qb][rg * 4 + 2] = b1.z; sv1[qb][rg * 4 + 3] = b1.w;
      }
    }

    // ---- S^T = K Q^T : K-frags shared across both q-blocks (DS reads halved/FLOP)
    __builtin_amdgcn_s_setprio(1);
#pragma unroll
    for (int t4 = 0; t4 < 4; ++t4) {
      int g = ((2 * t4 + h5) ^ rsw) * 8;
      short8_t kf0 = *(const short8_t*)&lK[cur][l31 * 64 + g];
      short8_t kf1 = *(const short8_t*)&lK[cur][(32 + l31) * 64 + g];
      sv0[0] = __builtin_amdgcn_mfma_f32_32x32x16_bf16(kf0, qf[0][t4], sv0[0], 0, 0, 0);
      sv0[1] = __builtin_amdgcn_mfma_f32_32x32x16_bf16(kf0, qf[1][t4], sv0[1], 0, 0, 0);
      sv1[0] = __builtin_amdgcn_mfma_f32_32x32x16_bf16(kf1, qf[0][t4], sv1[0], 0, 0, 0);
      sv1[1] = __builtin_amdgcn_mfma_f32_32x32x16_bf16(kf1, qf[1][t4], sv1[1], 0, 0, 0);
    }
    __builtin_amdgcn_s_setprio(0);

    // ---- online softmax per q-block (in-register, log2 domain; shfl_xor verified R2/R4)
    unsigned int pkw[2][16];
#pragma unroll
    for (int qb = 0; qb < 2; ++qb) {
      float tmx[8];
#pragma unroll
      for (int i = 0; i < 8; ++i)
        tmx[i] = fmaxf(fmaxf(sv0[qb][i], sv0[qb][i + 8]),
                       fmaxf(sv1[qb][i], sv1[qb][i + 8]));
#pragma unroll
      for (int i = 0; i < 4; ++i) tmx[i] = fmaxf(tmx[i], tmx[i + 4]);
      float tm = fmaxf(fmaxf(tmx[0], tmx[1]), fmaxf(tmx[2], tmx[3]));
      tm = fmaxf(tm, __shfl_xor(tm, 32));

      if (__any(tm > mrow[qb] + 8.0f)) {   // defer-max (T13)
        float mnew = fmaxf(mrow[qb], tm);
        float sc = __builtin_amdgcn_exp2f(mrow[qb] - mnew);
        mrow[qb] = mnew;
        lrow[qb] *= sc;
#pragma unroll
        for (int i = 0; i < 16; ++i) { acc0[qb][i] *= sc; acc1[qb][i] *= sc; }
      }

      float m = mrow[qb];
      float t0 = 0.f, t1 = 0.f, t2 = 0.f, t3 = 0.f;
#pragma unroll
      for (int i = 0; i < 16; i += 4) {
        sv0[qb][i + 0] = __builtin_amdgcn_exp2f(sv0[qb][i + 0] - m); t0 += sv0[qb][i + 0];
        sv0[qb][i + 1] = __builtin_amdgcn_exp2f(sv0[qb][i + 1] - m); t1 += sv0[qb][i + 1];
        sv0[qb][i + 2] = __builtin_amdgcn_exp2f(sv0[qb][i + 2] - m); t2 += sv0[qb][i + 2];
        sv0[qb][i + 3] = __builtin_amdgcn_exp2f(sv0[qb][i + 3] - m); t3 += sv0[qb][i + 3];
        sv1[qb][i + 0] = __builtin_amdgcn_exp2f(sv1[qb][i + 0] - m); t0 += sv1[qb][i + 0];
        sv1[qb][i + 1] = __builtin_amdgcn_exp2f(sv1[qb][i + 1] - m); t1 += sv1[qb][i + 1];
        sv1[qb][i + 2] = __builtin_amdgcn_exp2f(sv1[qb][i + 2] - m); t2 += sv1[qb][i + 2];
        sv1[qb][i + 3] = __builtin_amdgcn_exp2f(sv1[qb][i + 3] - m); t3 += sv1[qb][i + 3];
      }
      float ts = (t0 + t1) + (t2 + t3);
      ts += __shfl_xor(ts, 32);
      lrow[qb] += ts;

      // pack: pkw[qb][n*8+rg*2+c] = keys n*32 + rg*8 + 4*h5 + 2c, +1
#pragma unroll
      for (int rg = 0; rg < 4; ++rg) {
        __hip_bfloat162 a0 = __float22bfloat162_rn({sv0[qb][rg * 4 + 0], sv0[qb][rg * 4 + 1]});
        __hip_bfloat162 a1 = __float22bfloat162_rn({sv0[qb][rg * 4 + 2], sv0[qb][rg * 4 + 3]});
        __hip_bfloat162 b0 = __float22bfloat162_rn({sv1[qb][rg * 4 + 0], sv1[qb][rg * 4 + 1]});
        __hip_bfloat162 b1 = __float22bfloat162_rn({sv1[qb][rg * 4 + 2], sv1[qb][rg * 4 + 3]});
        pkw[qb][rg * 2 + 0] = *(unsigned int*)&a0;
        pkw[qb][rg * 2 + 1] = *(unsigned int*)&a1;
        pkw[qb][8 + rg * 2 + 0] = *(unsigned int*)&b0;
        pkw[qb][8 + rg * 2 + 1] = *(unsigned int*)&b1;
      }
    }

    // ---- O^T += V^T P : V-frags shared across q-blocks; half-swap redistribution
    // via shfl_xor + cndmask (bit-for-bit the R4-verified mapping)
    __builtin_amdgcn_s_setprio(1);
#pragma unroll
    for (int kt = 0; kt < 4; ++kt) {
      const int n = kt >> 1, k1 = kt & 1;
      int gv = ((2 * kt + h5) ^ rsw) * 8;
      short8_t vf0 = *(const short8_t*)&lV[cur][l31 * 64 + gv];
      short8_t vf1 = *(const short8_t*)&lV[cur][(32 + l31) * 64 + gv];
#pragma unroll
      for (int qb = 0; qb < 2; ++qb) {
        unsigned int sA = pkw[qb][n * 8 + (2 * k1 + h5) * 2 + 0];
        unsigned int sB = pkw[qb][n * 8 + (2 * k1 + h5) * 2 + 1];
        unsigned int xA = pkw[qb][n * 8 + (2 * k1 + (h5 ^ 1)) * 2 + 0];
        unsigned int xB = pkw[qb][n * 8 + (2 * k1 + (h5 ^ 1)) * 2 + 1];
        unsigned int pA = (unsigned int)__shfl_xor((int)xA, 32);
        unsigned int pB = (unsigned int)__shfl_xor((int)xB, 32);
        union { unsigned int u[4]; short8_t v; } bb;
        bb.u[0] = h5 ? pA : sA;   // keys from lower-half holders
        bb.u[1] = h5 ? pB : sB;
        bb.u[2] = h5 ? sA : pA;   // keys from upper-half holders
        bb.u[3] = h5 ? sB : pB;
        acc0[qb] = __builtin_amdgcn_mfma_f32_32x32x16_bf16(vf0, bb.v, acc0[qb], 0, 0, 0);
        acc1[qb] = __builtin_amdgcn_mfma_f32_32x32x16_bf16(vf1, bb.v, acc1[qb], 0, 0, 0);
      }
    }
    __builtin_amdgcn_s_setprio(0);

    __syncthreads();   // drains prefetch + separates buffers
  }

  // ---- epilogue: unnormalized partial O + (m,l) stats, per q-block
  float* Op = (ch == 0 ? Oa : Ob);
#pragma unroll
  for (int qb = 0; qb < 2; ++qb) {
    float* op = Op + ((size_t)bh * S_ + qrow0 + 32 * qb) * D_;
#pragma unroll
    for (int rg = 0; rg < 4; ++rg) {
      float4 o0, o1;
      o0.x = acc0[qb][rg * 4 + 0]; o0.y = acc0[qb][rg * 4 + 1];
      o0.z = acc0[qb][rg * 4 + 2]; o0.w = acc0[qb][rg * 4 + 3];
      o1.x = acc1[qb][rg * 4 + 0]; o1.y = acc1[qb][rg * 4 + 1];
      o1.z = acc1[qb][rg * 4 + 2]; o1.w = acc1[qb][rg * 4 + 3];
      *(float4*)(op + rg * 8 + h5 * 4) = o0;
      *(float4*)(op + 32 + rg * 8 + h5 * 4) = o1;
    }
    if (h5 == 0) {
      float2 st; st.x = mrow[qb]; st.y = lrow[qb];
      Ml[(size_t)ch * (BH_ * S_) + (size_t)bh * S_ + qrow0 + 32 * qb] = st;
    }
  }
}

// merge two KV-chunk partials: out = (O0*w0 + O1*w1) / (l0*w0 + l1*w1), wi = 2^(mi - M)
__global__ void combine_kernel(const float* __restrict__ O1, const float2* __restrict__ Ml,
                               float* __restrict__ out) {
  int gid = blockIdx.x * 256 + threadIdx.x;   // (row, 16-d quarter)
  int row = gid >> 2, qd = (gid & 3) * 16;
  float2 a = Ml[row];                    // chunk 0
  float2 b = Ml[BH_ * S_ + row];         // chunk 1
  float M = fmaxf(a.x, b.x);
  float w0 = exp2f(a.x - M), w1 = exp2f(b.x - M);
  float inv = 1.0f / (a.y * w0 + b.y * w1);
  w0 *= inv; w1 *= inv;
  const float4* p0 = (const float4*)(out + (size_t)row * D_ + qd);  // chunk0 partial in out
  const float4* p1 = (const float4*)(O1 + (size_t)row * D_ + qd);
  float4* po = (float4*)(out + (size_t)row * D_ + qd);
#pragma unroll
  for (int i = 0; i < 4; ++i) {
    float4 x = p0[i], y = p1[i];
    float4 r;
    r.x = x.x * w0 + y.x * w1; r.y = x.y * w0 + y.y * w1;
    r.z = x.z * w0 + y.z * w1; r.w = x.w * w0 + y.w * w1;
    po[i] = r;
  }
}

extern "C" void kernel_launch(void* const* d_in, const int* in_sizes, int n_in,
                              void* d_out, int out_size, void* d_ws, size_t ws_size,
                              hipStream_t stream) {
  const float* q_a = (const float*)d_in[0];
  const float* k_a = (const float*)d_in[1];
  const float* v_a = (const float*)d_in[2];
  const float* q_s = (const float*)d_in[3];
  const float* k_s = (const float*)d_in[4];
  const float* v_s = (const float*)d_in[5];
  const int*   mask = (const int*)d_in[6];
  float* out = (float*)d_out;
  (void)in_sizes; (void)n_in; (void)out_size; (void)ws_size;

  const int N = BH_ * S_ * D_;   // 4,194,304
  unsigned short* qb = (unsigned short*)d_ws;
  unsigned short* kb = qb + N;
  unsigned short* vt = kb + N;
  float* fb = (float*)(vt + N);          // 2*S_ floats
  float* O1 = fb + 2 * S_;               // N floats (chunk-1 partial; chunk-0 -> out)
  float2* ml = (float2*)(O1 + N);        // NCH * BH_*S_ float2

  addcvt2_kernel<<<N / 1024, 256, 0, stream>>>(q_a, q_s, qb, QSCALE, N);
  addcvt2_kernel<<<N / 1024, 256, 0, stream>>>(k_a, k_s, kb, 1.0f, N);
  {
    dim3 g(S_ / 64, BH_);
    vtrans_kernel<<<g, 256, 0, stream>>>(v_a, v_s, vt);
  }
  bias_kernel<<<(2 * S_) / 256, 256, 0, stream>>>(mask, fb, 2 * S_);
  {
    dim3 g(S_ / QBLK, BH_, NCH);
    attn_kernel<<<g, 256, 0, stream>>>(qb, kb, vt, fb, out, O1, ml);
  }
  combine_kernel<<<(BH_ * S_ * 4) / 256, 256, 0, stream>>>(O1, ml, out);
}